// Round 1
// baseline (4607.781 us; speedup 1.0000x reference)
//
#include <hip/hip_runtime.h>
#include <float.h>
#include <math.h>

#define NB 4            // graphs per batch
#define N0 40962        // nodes per graph at input
#define E0 983088       // total directed edges (fixed across layers; dead edges have w=0)

// ---------------- helpers ----------------

static __device__ __forceinline__ unsigned long long key64_of(float s, int li) {
    // monotone float->uint mapping (larger float => larger uint)
    unsigned u = __float_as_uint(s);
    u = (u & 0x80000000u) ? ~u : (u | 0x80000000u);
    // tie-break: smaller local index => larger key (preferred, matches top_k stability)
    unsigned low = ~(unsigned)li;
    return ((unsigned long long)u << 32) | (unsigned long long)low;
}

// ---------------- kernels ----------------

__global__ void k_edges_init(const int* __restrict__ ei, int* __restrict__ esrc,
                             int* __restrict__ edst, float* __restrict__ ew) {
    int e = blockIdx.x * blockDim.x + threadIdx.x;
    if (e >= E0) return;
    esrc[e] = ei[e];
    edst[e] = ei[E0 + e];
    ew[e] = 1.0f;
}

// h[m, fo] = sum_fi x[m, fi] * W[fi, fo]
__global__ void k_matmul(const float* __restrict__ x, const float* __restrict__ W,
                         float* __restrict__ h, int M, int Fi, int Fo) {
    int t = blockIdx.x * blockDim.x + threadIdx.x;
    if (t >= M * Fo) return;
    int m = t / Fo, fo = t - m * Fo;
    const float* xr = x + (size_t)m * Fi;
    float acc = 0.f;
    for (int fi = 0; fi < Fi; ++fi) acc = fmaf(xr[fi], W[fi * Fo + fo], acc);
    h[t] = acc;
}

__global__ void k_deg_init(float* __restrict__ deg, int M) {
    int m = blockIdx.x * blockDim.x + threadIdx.x;
    if (m < M) deg[m] = 1.0f;   // +1 self loop baked in
}

__global__ void k_deg_scatter(const int* __restrict__ edst, const float* __restrict__ ew,
                              float* __restrict__ deg) {
    int e = blockIdx.x * blockDim.x + threadIdx.x;
    if (e >= E0) return;
    float w = ew[e];
    if (w != 0.f) atomicAdd(&deg[edst[e]], w);
}

// y = h * (1/deg) + bias   (self-loop term + bias)
__global__ void k_y_init(const float* __restrict__ h, const float* __restrict__ deg,
                         const float* __restrict__ bias, float* __restrict__ y, int M, int Fo) {
    int t = blockIdx.x * blockDim.x + threadIdx.x;
    if (t >= M * Fo) return;
    int m = t / Fo, fo = t - m * Fo;
    y[t] = h[t] * (1.0f / deg[m]) + bias[fo];
}

// y[dst] += h[src] * rsqrt(deg[src]) * rsqrt(deg[dst]) * w   (thread per (edge, 4-feature chunk))
__global__ void k_scatter(const int* __restrict__ esrc, const int* __restrict__ edst,
                          const float* __restrict__ ew, const float* __restrict__ deg,
                          const float* __restrict__ h, float* __restrict__ y, int Fo4) {
    int t = blockIdx.x * blockDim.x + threadIdx.x;
    if (t >= E0 * Fo4) return;
    int e = t / Fo4, c = t - e * Fo4;
    float w = ew[e];
    if (w == 0.f) return;
    int s = esrc[e], d = edst[e];
    float norm = rsqrtf(deg[s]) * rsqrtf(deg[d]) * w;
    const float4 hv = ((const float4*)h)[(size_t)s * Fo4 + c];
    float* yp = y + ((size_t)d * Fo4 + c) * 4;
    atomicAdd(yp + 0, hv.x * norm);
    atomicAdd(yp + 1, hv.y * norm);
    atomicAdd(yp + 2, hv.z * norm);
    atomicAdd(yp + 3, hv.w * norm);
}

// in-place relu + score[m] = dot(relu(y[m]), p) / |p|
__global__ void k_relu_score(float* __restrict__ y, const float* __restrict__ p,
                             float* __restrict__ score, int M, int Fo) {
    int m = blockIdx.x * blockDim.x + threadIdx.x;
    if (m >= M) return;
    float* yr = y + (size_t)m * Fo;
    float dot = 0.f, pn = 0.f;
    for (int f = 0; f < Fo; ++f) {
        float v = yr[f];
        v = v > 0.f ? v : 0.f;
        yr[f] = v;
        float pf = p[f];
        dot = fmaf(v, pf, dot);
        pn = fmaf(pf, pf, pn);
    }
    score[m] = dot * rsqrtf(pn);
}

// one block per graph: radix-select the k-th largest composite key -> T64[b]; zero cnt[b]
__global__ void k_topk_thresh(const float* __restrict__ score, unsigned long long* __restrict__ T64,
                              int* __restrict__ cnt, int n, int k) {
    int b = blockIdx.x;
    const float* sc = score + (size_t)b * n;
    __shared__ unsigned int hist[256];
    __shared__ unsigned long long s_prefix;
    __shared__ int s_r;
    if (threadIdx.x == 0) { s_prefix = 0ULL; s_r = k; }
    __syncthreads();
    for (int shift = 56; shift >= 0; shift -= 8) {
        for (int i = threadIdx.x; i < 256; i += blockDim.x) hist[i] = 0u;
        __syncthreads();
        unsigned long long prefix = s_prefix;
        int hs = shift + 8;
        for (int i = threadIdx.x; i < n; i += blockDim.x) {
            unsigned long long key = key64_of(sc[i], i);
            bool match = (hs >= 64) || ((key >> hs) == (prefix >> hs));
            if (match) {
                unsigned d = (unsigned)((key >> shift) & 255ULL);
                atomicAdd(&hist[d], 1u);
            }
        }
        __syncthreads();
        if (threadIdx.x == 0) {
            int r = s_r;
            unsigned long long pfx = s_prefix;
            for (int d = 255; d >= 0; --d) {
                int c = (int)hist[d];
                if (r <= c) { pfx |= ((unsigned long long)d) << shift; break; }
                r -= c;
            }
            s_prefix = pfx;
            s_r = r;
        }
        __syncthreads();
    }
    if (threadIdx.x == 0) { T64[b] = s_prefix; cnt[b] = 0; }
}

// keep nodes with key >= T64[b]; assign arbitrary bijective new ids; xout = y * tanh(score)
__global__ void k_select(const float* __restrict__ y, const float* __restrict__ score,
                         const unsigned long long* __restrict__ T64, int* __restrict__ cnt,
                         int* __restrict__ remap, float* __restrict__ xout,
                         int M, int n, int k, int Fo) {
    int m = blockIdx.x * blockDim.x + threadIdx.x;
    if (m >= M) return;
    int b = m / n, i = m - b * n;
    unsigned long long key = key64_of(score[m], i);
    if (key >= T64[b]) {
        int j = atomicAdd(&cnt[b], 1);
        int ni = b * k + j;
        remap[m] = ni;
        float t = tanhf(score[m]);
        const float* yr = y + (size_t)m * Fo;
        float* xr = xout + (size_t)ni * Fo;
        for (int f = 0; f < Fo; ++f) xr[f] = yr[f] * t;
    } else {
        remap[m] = -1;
    }
}

__global__ void k_edge_remap(int* __restrict__ esrc, int* __restrict__ edst,
                             float* __restrict__ ew, const int* __restrict__ remap) {
    int e = blockIdx.x * blockDim.x + threadIdx.x;
    if (e >= E0) return;
    float w = ew[e];
    if (w != 0.f) {
        int ns = remap[esrc[e]];
        int nd = remap[edst[e]];
        if (ns >= 0 && nd >= 0) { esrc[e] = ns; edst[e] = nd; return; }
    }
    esrc[e] = 0; edst[e] = 0; ew[e] = 0.f;
}

// one block (128 threads) per graph: max/mean pool over K3 nodes + metadata conv + fc + fc2
__global__ void k_final(const float* __restrict__ x, const float* __restrict__ metadata,
                        const float* __restrict__ convm_w, const float* __restrict__ convm_b,
                        const float* __restrict__ fc_w, const float* __restrict__ fc_b,
                        const float* __restrict__ fc2_w, const float* __restrict__ fc2_b,
                        float* __restrict__ out, int K3) {
    int b = blockIdx.x;
    int f = threadIdx.x;   // 0..127
    __shared__ float xc[260];
    __shared__ float red[128];
    const float* xb = x + (size_t)b * K3 * 128;
    float mx = -FLT_MAX, sm = 0.f;
    for (int i = 0; i < K3; ++i) {
        float v = xb[(size_t)i * 128 + f];
        mx = fmaxf(mx, v);
        sm += v;
    }
    xc[f] = mx;
    xc[128 + f] = sm / (float)K3;
    if (f < 4) {
        float mv = metadata[b] * convm_w[f] + convm_b[f];
        xc[256 + f] = mv > 0.f ? mv : 0.f;
    }
    __syncthreads();
    float acc = fc_b[f];
    for (int i = 0; i < 260; ++i) acc = fmaf(xc[i], fc_w[i * 128 + f], acc);
    acc = acc > 0.f ? acc : 0.f;
    red[f] = acc * fc2_w[f];
    __syncthreads();
    for (int s2 = 64; s2 > 0; s2 >>= 1) {
        if (f < s2) red[f] += red[f + s2];
        __syncthreads();
    }
    if (f == 0) out[b] = red[0] + fc2_b[0];
}

// ---------------- launch ----------------

extern "C" void kernel_launch(void* const* d_in, const int* in_sizes, int n_in,
                              void* d_out, int out_size, void* d_ws, size_t ws_size,
                              hipStream_t stream) {
    const float* x0       = (const float*)d_in[0];
    const int*   ei       = (const int*)d_in[1];
    const float* metadata = (const float*)d_in[2];
    const float* W[4]  = {(const float*)d_in[3], (const float*)d_in[6],
                          (const float*)d_in[9], (const float*)d_in[12]};
    const float* bs[4] = {(const float*)d_in[4], (const float*)d_in[7],
                          (const float*)d_in[10], (const float*)d_in[13]};
    const float* pv[4] = {(const float*)d_in[5], (const float*)d_in[8],
                          (const float*)d_in[11], (const float*)d_in[14]};
    const float* convm_w = (const float*)d_in[15];
    const float* convm_b = (const float*)d_in[16];
    const float* fc_w    = (const float*)d_in[17];
    const float* fc_b    = (const float*)d_in[18];
    const float* fc2_w   = (const float*)d_in[19];
    const float* fc2_b   = (const float*)d_in[20];

    // workspace bump allocation (all sizes in elements)
    const size_t HMAX = 5243392;   // max M*Fo over layers (layer 3: 40964*128)
    const size_t XMAX = 2621952;   // max pooled-x size (layer 3 out: 20484*128)
    const size_t MMAX = NB * (size_t)N0;   // 163848

    char* p = (char*)d_ws;
    size_t off = 0;
    auto alloc = [&](size_t bytes) -> char* {
        char* r = p + off;
        off = (off + bytes + 255) & ~(size_t)255;
        return r;
    };
    float* h     = (float*)alloc(HMAX * 4);
    float* y     = (float*)alloc(HMAX * 4);
    float* xb0   = (float*)alloc(XMAX * 4);
    float* xb1   = (float*)alloc(XMAX * 4);
    float* deg   = (float*)alloc(MMAX * 4);
    float* score = (float*)alloc(MMAX * 4);
    int*   remap = (int*)alloc(MMAX * 4);
    int*   esrc  = (int*)alloc(E0 * 4);
    int*   edst  = (int*)alloc(E0 * 4);
    float* ew    = (float*)alloc(E0 * 4);
    unsigned long long* T64 = (unsigned long long*)alloc(NB * 8);
    int*   cnt   = (int*)alloc(NB * 4);
    (void)ws_size; (void)n_in; (void)in_sizes; (void)out_size;

    const int Fi[4] = {4, 32, 64, 128};
    const int Fo[4] = {32, 64, 128, 128};
    const int Kk[4] = {20481, 10241, 5121, 2561};

    const int TB = 256;
    k_edges_init<<<(E0 + TB - 1) / TB, TB, 0, stream>>>(ei, esrc, edst, ew);

    int M = NB * N0;
    const float* xin = x0;
    float* xbufs[2] = {xb0, xb1};

    for (int L = 0; L < 4; ++L) {
        int fi = Fi[L], fo = Fo[L];
        int MF = M * fo;
        k_matmul<<<(MF + TB - 1) / TB, TB, 0, stream>>>(xin, W[L], h, M, fi, fo);
        k_deg_init<<<(M + TB - 1) / TB, TB, 0, stream>>>(deg, M);
        k_deg_scatter<<<(E0 + TB - 1) / TB, TB, 0, stream>>>(edst, ew, deg);
        k_y_init<<<(MF + TB - 1) / TB, TB, 0, stream>>>(h, deg, bs[L], y, M, fo);
        int tot = E0 * (fo / 4);
        k_scatter<<<(tot + TB - 1) / TB, TB, 0, stream>>>(esrc, edst, ew, deg, h, y, fo / 4);
        k_relu_score<<<(M + TB - 1) / TB, TB, 0, stream>>>(y, pv[L], score, M, fo);

        int n = M / NB, kk = Kk[L];
        k_topk_thresh<<<NB, 256, 0, stream>>>(score, T64, cnt, n, kk);
        float* xout = xbufs[L & 1];
        k_select<<<(M + TB - 1) / TB, TB, 0, stream>>>(y, score, T64, cnt, remap, xout,
                                                       M, n, kk, fo);
        if (L < 3)
            k_edge_remap<<<(E0 + TB - 1) / TB, TB, 0, stream>>>(esrc, edst, ew, remap);

        M = NB * kk;
        xin = xout;
    }

    k_final<<<NB, 128, 0, stream>>>(xin, metadata, convm_w, convm_b, fc_w, fc_b,
                                    fc2_w, fc2_b, (float*)d_out, Kk[3]);
}

// Round 2
// 2501.605 us; speedup vs baseline: 1.8419x; 1.8419x over previous
//
#include <hip/hip_runtime.h>
#include <float.h>
#include <math.h>

#define NB 4            // graphs per batch
#define N0 40962        // nodes per graph at input
#define E0 983088       // total directed edges (fixed across layers; dead edges have w=0)

// ---------------- helpers ----------------

static __device__ __forceinline__ unsigned long long key64_of(float s, int li) {
    // monotone float->uint mapping (larger float => larger uint)
    unsigned u = __float_as_uint(s);
    u = (u & 0x80000000u) ? ~u : (u | 0x80000000u);
    // tie-break: smaller local index => larger key (ties at score==0.0 are real: all-zero relu rows)
    unsigned low = ~(unsigned)li;
    return ((unsigned long long)u << 32) | (unsigned long long)low;
}

// ---------------- kernels ----------------

__global__ void k_edges_init(const int* __restrict__ ei, int* __restrict__ esrc,
                             int* __restrict__ edst, float* __restrict__ ew) {
    int e = blockIdx.x * blockDim.x + threadIdx.x;
    if (e >= E0) return;
    esrc[e] = ei[e];
    edst[e] = ei[E0 + e];
    ew[e] = 1.0f;
}

// h[m, fo] = sum_fi x[m, fi] * W[fi, fo]
__global__ void k_matmul(const float* __restrict__ x, const float* __restrict__ W,
                         float* __restrict__ h, int M, int Fi, int Fo) {
    int t = blockIdx.x * blockDim.x + threadIdx.x;
    if (t >= M * Fo) return;
    int m = t / Fo, fo = t - m * Fo;
    const float* xr = x + (size_t)m * Fi;
    float acc = 0.f;
    for (int fi = 0; fi < Fi; ++fi) acc = fmaf(xr[fi], W[fi * Fo + fo], acc);
    h[t] = acc;
}

__global__ void k_deg_init(float* __restrict__ deg, int M) {
    int m = blockIdx.x * blockDim.x + threadIdx.x;
    if (m < M) deg[m] = 1.0f;   // +1 self loop baked in
}

__global__ void k_deg_scatter(const int* __restrict__ edst, const float* __restrict__ ew,
                              float* __restrict__ deg) {
    int e = blockIdx.x * blockDim.x + threadIdx.x;
    if (e >= E0) return;
    float w = ew[e];
    if (w != 0.f) atomicAdd(&deg[edst[e]], w);
}

// y = h * (1/deg) + bias   (self-loop term + bias)
__global__ void k_y_init(const float* __restrict__ h, const float* __restrict__ deg,
                         const float* __restrict__ bias, float* __restrict__ y, int M, int Fo) {
    int t = blockIdx.x * blockDim.x + threadIdx.x;
    if (t >= M * Fo) return;
    int m = t / Fo, fo = t - m * Fo;
    y[t] = h[t] * (1.0f / deg[m]) + bias[fo];
}

// y[dst] += h[src] * rsqrt(deg[src]) * rsqrt(deg[dst]) * w   (thread per (edge, 4-feature chunk))
__global__ void k_scatter(const int* __restrict__ esrc, const int* __restrict__ edst,
                          const float* __restrict__ ew, const float* __restrict__ deg,
                          const float* __restrict__ h, float* __restrict__ y, int Fo4) {
    int t = blockIdx.x * blockDim.x + threadIdx.x;
    if (t >= E0 * Fo4) return;
    int e = t / Fo4, c = t - e * Fo4;
    float w = ew[e];
    if (w == 0.f) return;
    int s = esrc[e], d = edst[e];
    float norm = rsqrtf(deg[s]) * rsqrtf(deg[d]) * w;
    const float4 hv = ((const float4*)h)[(size_t)s * Fo4 + c];
    float* yp = y + ((size_t)d * Fo4 + c) * 4;
    atomicAdd(yp + 0, hv.x * norm);
    atomicAdd(yp + 1, hv.y * norm);
    atomicAdd(yp + 2, hv.z * norm);
    atomicAdd(yp + 3, hv.w * norm);
}

// in-place relu + score[m] = dot(relu(y[m]), p) / |p|
__global__ void k_relu_score(float* __restrict__ y, const float* __restrict__ p,
                             float* __restrict__ score, int M, int Fo) {
    int m = blockIdx.x * blockDim.x + threadIdx.x;
    if (m >= M) return;
    float* yr = y + (size_t)m * Fo;
    float dot = 0.f, pn = 0.f;
    for (int f = 0; f < Fo; ++f) {
        float v = yr[f];
        v = v > 0.f ? v : 0.f;
        yr[f] = v;
        float pf = p[f];
        dot = fmaf(v, pf, dot);
        pn = fmaf(pf, pf, pn);
    }
    score[m] = dot * rsqrtf(pn);
}

// one block (1024 threads) per graph: radix-select the k-th largest composite key -> T64[b];
// zero cnt[b]. Early-exits when the k-th key's prefix is unique at some level.
__global__ void k_topk_thresh(const float* __restrict__ score, unsigned long long* __restrict__ T64,
                              int* __restrict__ cnt, int n, int k) {
    int b = blockIdx.x;
    const float* sc = score + (size_t)b * n;
    __shared__ unsigned int hist[256];
    __shared__ unsigned long long s_prefix;
    __shared__ int s_r;
    __shared__ int s_done;
    if (threadIdx.x == 0) { s_prefix = 0ULL; s_r = k; s_done = 0; }
    __syncthreads();
    for (int shift = 56; shift >= 0; shift -= 8) {
        if (s_done) break;
        for (int i = threadIdx.x; i < 256; i += blockDim.x) hist[i] = 0u;
        __syncthreads();
        unsigned long long prefix = s_prefix;
        int hs = shift + 8;
        for (int i = threadIdx.x; i < n; i += blockDim.x) {
            unsigned long long key = key64_of(sc[i], i);
            bool match = (hs >= 64) || ((key >> hs) == (prefix >> hs));
            if (match) {
                unsigned d = (unsigned)((key >> shift) & 255ULL);
                atomicAdd(&hist[d], 1u);
            }
        }
        __syncthreads();
        if (threadIdx.x == 0) {
            int r = s_r;
            unsigned long long pfx = s_prefix;
            for (int d = 255; d >= 0; --d) {
                int c = (int)hist[d];
                if (r <= c) {
                    pfx |= ((unsigned long long)d) << shift;
                    if (r == c) s_done = 1;   // all prefix-matching keys kept; low bits stay 0
                    break;
                }
                r -= c;
            }
            s_prefix = pfx;
            s_r = r;
        }
        __syncthreads();
    }
    if (threadIdx.x == 0) { T64[b] = s_prefix; cnt[b] = 0; }
}

// phase A: keep flag -> new index via wave-aggregated block atomic; score := tanh(score) for kept
// grid: (ceil(n/256), NB), block 256 (4 waves)
__global__ void k_select_idx(float* __restrict__ score,
                             const unsigned long long* __restrict__ T64, int* __restrict__ cnt,
                             int* __restrict__ remap, int n, int k) {
    int b = blockIdx.y;
    int i = blockIdx.x * 256 + threadIdx.x;
    int m = b * n + i;
    bool keep = false;
    float s = 0.f;
    if (i < n) {
        s = score[m];
        keep = key64_of(s, i) >= T64[b];
    }
    unsigned long long mask = __ballot(keep);
    int lane = threadIdx.x & 63;
    int wv = threadIdx.x >> 6;
    int lp = __popcll(mask & ((1ULL << lane) - 1ULL));
    __shared__ int woff[4];
    __shared__ int blockBase;
    if (lane == 0) woff[wv] = __popcll(mask);
    __syncthreads();
    if (threadIdx.x == 0) {
        int t0 = woff[0], t1 = woff[1], t2 = woff[2], t3 = woff[3];
        woff[0] = 0; woff[1] = t0; woff[2] = t0 + t1; woff[3] = t0 + t1 + t2;
        blockBase = atomicAdd(&cnt[b], t0 + t1 + t2 + t3);
    }
    __syncthreads();
    if (i < n) {
        if (keep) {
            remap[m] = b * k + blockBase + woff[wv] + lp;
            score[m] = tanhf(s);
        } else {
            remap[m] = -1;
        }
    }
}

// phase B: coalesced float4 row copy, xout[remap[m]] = y[m] * score[m] (score holds tanh)
__global__ void k_select_copy(const float* __restrict__ y, const float* __restrict__ score,
                              const int* __restrict__ remap, float* __restrict__ xout,
                              int M, int Fo4) {
    int t = blockIdx.x * blockDim.x + threadIdx.x;
    if (t >= M * Fo4) return;
    int m = t / Fo4, c = t - m * Fo4;
    int ni = remap[m];
    if (ni < 0) return;
    float4 v = ((const float4*)y)[(size_t)m * Fo4 + c];
    float s = score[m];
    float4 o; o.x = v.x * s; o.y = v.y * s; o.z = v.z * s; o.w = v.w * s;
    ((float4*)xout)[(size_t)ni * Fo4 + c] = o;
}

__global__ void k_edge_remap(int* __restrict__ esrc, int* __restrict__ edst,
                             float* __restrict__ ew, const int* __restrict__ remap) {
    int e = blockIdx.x * blockDim.x + threadIdx.x;
    if (e >= E0) return;
    float w = ew[e];
    if (w != 0.f) {
        int ns = remap[esrc[e]];
        int nd = remap[edst[e]];
        if (ns >= 0 && nd >= 0) { esrc[e] = ns; edst[e] = nd; return; }
    }
    esrc[e] = 0; edst[e] = 0; ew[e] = 0.f;
}

// one block (128 threads) per graph: max/mean pool over K3 nodes + metadata conv + fc + fc2
__global__ void k_final(const float* __restrict__ x, const float* __restrict__ metadata,
                        const float* __restrict__ convm_w, const float* __restrict__ convm_b,
                        const float* __restrict__ fc_w, const float* __restrict__ fc_b,
                        const float* __restrict__ fc2_w, const float* __restrict__ fc2_b,
                        float* __restrict__ out, int K3) {
    int b = blockIdx.x;
    int f = threadIdx.x;   // 0..127
    __shared__ float xc[260];
    __shared__ float red[128];
    const float* xb = x + (size_t)b * K3 * 128;
    float mx = -FLT_MAX, sm = 0.f;
    for (int i = 0; i < K3; ++i) {
        float v = xb[(size_t)i * 128 + f];
        mx = fmaxf(mx, v);
        sm += v;
    }
    xc[f] = mx;
    xc[128 + f] = sm / (float)K3;
    if (f < 4) {
        float mv = metadata[b] * convm_w[f] + convm_b[f];
        xc[256 + f] = mv > 0.f ? mv : 0.f;
    }
    __syncthreads();
    float acc = fc_b[f];
    for (int i = 0; i < 260; ++i) acc = fmaf(xc[i], fc_w[i * 128 + f], acc);
    acc = acc > 0.f ? acc : 0.f;
    red[f] = acc * fc2_w[f];
    __syncthreads();
    for (int s2 = 64; s2 > 0; s2 >>= 1) {
        if (f < s2) red[f] += red[f + s2];
        __syncthreads();
    }
    if (f == 0) out[b] = red[0] + fc2_b[0];
}

// ---------------- launch ----------------

extern "C" void kernel_launch(void* const* d_in, const int* in_sizes, int n_in,
                              void* d_out, int out_size, void* d_ws, size_t ws_size,
                              hipStream_t stream) {
    const float* x0       = (const float*)d_in[0];
    const int*   ei       = (const int*)d_in[1];
    const float* metadata = (const float*)d_in[2];
    const float* W[4]  = {(const float*)d_in[3], (const float*)d_in[6],
                          (const float*)d_in[9], (const float*)d_in[12]};
    const float* bs[4] = {(const float*)d_in[4], (const float*)d_in[7],
                          (const float*)d_in[10], (const float*)d_in[13]};
    const float* pv[4] = {(const float*)d_in[5], (const float*)d_in[8],
                          (const float*)d_in[11], (const float*)d_in[14]};
    const float* convm_w = (const float*)d_in[15];
    const float* convm_b = (const float*)d_in[16];
    const float* fc_w    = (const float*)d_in[17];
    const float* fc_b    = (const float*)d_in[18];
    const float* fc2_w   = (const float*)d_in[19];
    const float* fc2_b   = (const float*)d_in[20];

    // workspace bump allocation (all sizes in elements)
    const size_t HMAX = 5243392;   // max M*Fo over layers (layer 3: 40964*128)
    const size_t XMAX = 2621952;   // max pooled-x size (layer 3 out: 20484*128)
    const size_t MMAX = NB * (size_t)N0;   // 163848

    char* p = (char*)d_ws;
    size_t off = 0;
    auto alloc = [&](size_t bytes) -> char* {
        char* r = p + off;
        off = (off + bytes + 255) & ~(size_t)255;
        return r;
    };
    float* h     = (float*)alloc(HMAX * 4);
    float* y     = (float*)alloc(HMAX * 4);
    float* xb0   = (float*)alloc(XMAX * 4);
    float* xb1   = (float*)alloc(XMAX * 4);
    float* deg   = (float*)alloc(MMAX * 4);
    float* score = (float*)alloc(MMAX * 4);
    int*   remap = (int*)alloc(MMAX * 4);
    int*   esrc  = (int*)alloc(E0 * 4);
    int*   edst  = (int*)alloc(E0 * 4);
    float* ew    = (float*)alloc(E0 * 4);
    unsigned long long* T64 = (unsigned long long*)alloc(NB * 8);
    int*   cnt   = (int*)alloc(NB * 4);
    (void)ws_size; (void)n_in; (void)in_sizes; (void)out_size;

    const int Fi[4] = {4, 32, 64, 128};
    const int Fo[4] = {32, 64, 128, 128};
    const int Kk[4] = {20481, 10241, 5121, 2561};

    const int TB = 256;
    k_edges_init<<<(E0 + TB - 1) / TB, TB, 0, stream>>>(ei, esrc, edst, ew);

    int M = NB * N0;
    const float* xin = x0;
    float* xbufs[2] = {xb0, xb1};

    for (int L = 0; L < 4; ++L) {
        int fi = Fi[L], fo = Fo[L];
        int MF = M * fo;
        k_matmul<<<(MF + TB - 1) / TB, TB, 0, stream>>>(xin, W[L], h, M, fi, fo);
        k_deg_init<<<(M + TB - 1) / TB, TB, 0, stream>>>(deg, M);
        k_deg_scatter<<<(E0 + TB - 1) / TB, TB, 0, stream>>>(edst, ew, deg);
        k_y_init<<<(MF + TB - 1) / TB, TB, 0, stream>>>(h, deg, bs[L], y, M, fo);
        int tot = E0 * (fo / 4);
        k_scatter<<<(tot + TB - 1) / TB, TB, 0, stream>>>(esrc, edst, ew, deg, h, y, fo / 4);
        k_relu_score<<<(M + TB - 1) / TB, TB, 0, stream>>>(y, pv[L], score, M, fo);

        int n = M / NB, kk = Kk[L];
        k_topk_thresh<<<NB, 1024, 0, stream>>>(score, T64, cnt, n, kk);
        dim3 gsel((n + 255) / 256, NB);
        k_select_idx<<<gsel, 256, 0, stream>>>(score, T64, cnt, remap, n, kk);
        float* xout = xbufs[L & 1];
        int ctot = M * (fo / 4);
        k_select_copy<<<(ctot + TB - 1) / TB, TB, 0, stream>>>(y, score, remap, xout,
                                                               M, fo / 4);
        if (L < 3)
            k_edge_remap<<<(E0 + TB - 1) / TB, TB, 0, stream>>>(esrc, edst, ew, remap);

        M = NB * kk;
        xin = xout;
    }

    k_final<<<NB, 128, 0, stream>>>(xin, metadata, convm_w, convm_b, fc_w, fc_b,
                                    fc2_w, fc2_b, (float*)d_out, Kk[3]);
}

// Round 3
// 1875.432 us; speedup vs baseline: 2.4569x; 1.3339x over previous
//
#include <hip/hip_runtime.h>
#include <float.h>
#include <math.h>

#define NB 4            // graphs per batch
#define N0 40962        // nodes per graph at input
#define E0 983088       // total directed edges (fixed across layers; dead edges have w=0)
#define PCHUNKS 40      // stage-1 pooling blocks per graph

// ---------------- helpers ----------------

static __device__ __forceinline__ unsigned long long key64_of(float s, int li) {
    // monotone float->uint mapping (larger float => larger uint)
    unsigned u = __float_as_uint(s);
    u = (u & 0x80000000u) ? ~u : (u | 0x80000000u);
    // tie-break: smaller local index => larger key (ties at score==0.0 are real: all-zero relu rows)
    unsigned low = ~(unsigned)li;
    return ((unsigned long long)u << 32) | (unsigned long long)low;
}

// ---------------- kernels ----------------

__global__ void k_edges_init(const int* __restrict__ ei, int* __restrict__ esrc,
                             int* __restrict__ edst, float* __restrict__ ew) {
    int e = blockIdx.x * blockDim.x + threadIdx.x;
    if (e >= E0) return;
    esrc[e] = ei[e];
    edst[e] = ei[E0 + e];
    ew[e] = 1.0f;
}

// h[m, fo] = sum_fi x[m, fi] * W[fi, fo]
__global__ void k_matmul(const float* __restrict__ x, const float* __restrict__ W,
                         float* __restrict__ h, int M, int Fi, int Fo) {
    int t = blockIdx.x * blockDim.x + threadIdx.x;
    if (t >= M * Fo) return;
    int m = t / Fo, fo = t - m * Fo;
    const float* xr = x + (size_t)m * Fi;
    float acc = 0.f;
    for (int fi = 0; fi < Fi; ++fi) acc = fmaf(xr[fi], W[fi * Fo + fo], acc);
    h[t] = acc;
}

__global__ void k_deg_init(float* __restrict__ deg, int M) {
    int m = blockIdx.x * blockDim.x + threadIdx.x;
    if (m < M) deg[m] = 1.0f;   // +1 self loop baked in
}

__global__ void k_deg_scatter(const int* __restrict__ edst, const float* __restrict__ ew,
                              float* __restrict__ deg) {
    int e = blockIdx.x * blockDim.x + threadIdx.x;
    if (e >= E0) return;
    float w = ew[e];
    if (w != 0.f) atomicAdd(&deg[edst[e]], w);
}

// y = h * (1/deg) + bias   (self-loop term + bias)
__global__ void k_y_init(const float* __restrict__ h, const float* __restrict__ deg,
                         const float* __restrict__ bias, float* __restrict__ y, int M, int Fo) {
    int t = blockIdx.x * blockDim.x + threadIdx.x;
    if (t >= M * Fo) return;
    int m = t / Fo, fo = t - m * Fo;
    y[t] = h[t] * (1.0f / deg[m]) + bias[fo];
}

// y[dst] += h[src] * rsqrt(deg[src]) * rsqrt(deg[dst]) * w   (thread per (edge, 4-feature chunk))
__global__ void k_scatter(const int* __restrict__ esrc, const int* __restrict__ edst,
                          const float* __restrict__ ew, const float* __restrict__ deg,
                          const float* __restrict__ h, float* __restrict__ y, int Fo4) {
    int t = blockIdx.x * blockDim.x + threadIdx.x;
    if (t >= E0 * Fo4) return;
    int e = t / Fo4, c = t - e * Fo4;
    float w = ew[e];
    if (w == 0.f) return;
    int s = esrc[e], d = edst[e];
    float norm = rsqrtf(deg[s]) * rsqrtf(deg[d]) * w;
    const float4 hv = ((const float4*)h)[(size_t)s * Fo4 + c];
    float* yp = y + ((size_t)d * Fo4 + c) * 4;
    atomicAdd(yp + 0, hv.x * norm);
    atomicAdd(yp + 1, hv.y * norm);
    atomicAdd(yp + 2, hv.z * norm);
    atomicAdd(yp + 3, hv.w * norm);
}

// in-place relu + score[m] = dot(relu(y[m]), p) / |p|
__global__ void k_relu_score(float* __restrict__ y, const float* __restrict__ p,
                             float* __restrict__ score, int M, int Fo) {
    int m = blockIdx.x * blockDim.x + threadIdx.x;
    if (m >= M) return;
    float* yr = y + (size_t)m * Fo;
    float dot = 0.f, pn = 0.f;
    for (int f = 0; f < Fo; ++f) {
        float v = yr[f];
        v = v > 0.f ? v : 0.f;
        yr[f] = v;
        float pf = p[f];
        dot = fmaf(v, pf, dot);
        pn = fmaf(pf, pf, pn);
    }
    score[m] = dot * rsqrtf(pn);
}

// one block (1024 threads) per graph: radix-select the k-th largest composite key -> T64[b];
// zero cnt[b]. Early-exits when the k-th key's prefix is unique at some level.
__global__ void k_topk_thresh(const float* __restrict__ score, unsigned long long* __restrict__ T64,
                              int* __restrict__ cnt, int n, int k) {
    int b = blockIdx.x;
    const float* sc = score + (size_t)b * n;
    __shared__ unsigned int hist[256];
    __shared__ unsigned long long s_prefix;
    __shared__ int s_r;
    __shared__ int s_done;
    if (threadIdx.x == 0) { s_prefix = 0ULL; s_r = k; s_done = 0; }
    __syncthreads();
    for (int shift = 56; shift >= 0; shift -= 8) {
        if (s_done) break;
        for (int i = threadIdx.x; i < 256; i += blockDim.x) hist[i] = 0u;
        __syncthreads();
        unsigned long long prefix = s_prefix;
        int hs = shift + 8;
        for (int i = threadIdx.x; i < n; i += blockDim.x) {
            unsigned long long key = key64_of(sc[i], i);
            bool match = (hs >= 64) || ((key >> hs) == (prefix >> hs));
            if (match) {
                unsigned d = (unsigned)((key >> shift) & 255ULL);
                atomicAdd(&hist[d], 1u);
            }
        }
        __syncthreads();
        if (threadIdx.x == 0) {
            int r = s_r;
            unsigned long long pfx = s_prefix;
            for (int d = 255; d >= 0; --d) {
                int c = (int)hist[d];
                if (r <= c) {
                    pfx |= ((unsigned long long)d) << shift;
                    if (r == c) s_done = 1;   // all prefix-matching keys kept; low bits stay 0
                    break;
                }
                r -= c;
            }
            s_prefix = pfx;
            s_r = r;
        }
        __syncthreads();
    }
    if (threadIdx.x == 0) { T64[b] = s_prefix; cnt[b] = 0; }
}

// phase A: keep flag -> new index via wave-aggregated block atomic; score := tanh(score) for kept
// grid: (ceil(n/256), NB), block 256 (4 waves)
__global__ void k_select_idx(float* __restrict__ score,
                             const unsigned long long* __restrict__ T64, int* __restrict__ cnt,
                             int* __restrict__ remap, int n, int k) {
    int b = blockIdx.y;
    int i = blockIdx.x * 256 + threadIdx.x;
    int m = b * n + i;
    bool keep = false;
    float s = 0.f;
    if (i < n) {
        s = score[m];
        keep = key64_of(s, i) >= T64[b];
    }
    unsigned long long mask = __ballot(keep);
    int lane = threadIdx.x & 63;
    int wv = threadIdx.x >> 6;
    int lp = __popcll(mask & ((1ULL << lane) - 1ULL));
    __shared__ int woff[4];
    __shared__ int blockBase;
    if (lane == 0) woff[wv] = __popcll(mask);
    __syncthreads();
    if (threadIdx.x == 0) {
        int t0 = woff[0], t1 = woff[1], t2 = woff[2], t3 = woff[3];
        woff[0] = 0; woff[1] = t0; woff[2] = t0 + t1; woff[3] = t0 + t1 + t2;
        blockBase = atomicAdd(&cnt[b], t0 + t1 + t2 + t3);
    }
    __syncthreads();
    if (i < n) {
        if (keep) {
            remap[m] = b * k + blockBase + woff[wv] + lp;
            score[m] = tanhf(s);
        } else {
            remap[m] = -1;
        }
    }
}

// phase B: coalesced float4 row copy, xout[remap[m]] = y[m] * score[m] (score holds tanh)
__global__ void k_select_copy(const float* __restrict__ y, const float* __restrict__ score,
                              const int* __restrict__ remap, float* __restrict__ xout,
                              int M, int Fo4) {
    int t = blockIdx.x * blockDim.x + threadIdx.x;
    if (t >= M * Fo4) return;
    int m = t / Fo4, c = t - m * Fo4;
    int ni = remap[m];
    if (ni < 0) return;
    float4 v = ((const float4*)y)[(size_t)m * Fo4 + c];
    float s = score[m];
    float4 o; o.x = v.x * s; o.y = v.y * s; o.z = v.z * s; o.w = v.w * s;
    ((float4*)xout)[(size_t)ni * Fo4 + c] = o;
}

__global__ void k_edge_remap(int* __restrict__ esrc, int* __restrict__ edst,
                             float* __restrict__ ew, const int* __restrict__ remap) {
    int e = blockIdx.x * blockDim.x + threadIdx.x;
    if (e >= E0) return;
    float w = ew[e];
    if (w != 0.f) {
        int ns = remap[esrc[e]];
        int nd = remap[edst[e]];
        if (ns >= 0 && nd >= 0) { esrc[e] = ns; edst[e] = nd; return; }
    }
    esrc[e] = 0; edst[e] = 0; ew[e] = 0.f;
}

// stage 1 of final pooling: grid (PCHUNKS, NB), block 128.
// block (c, b) pools nodes [c*chunk, min(K3, (c+1)*chunk)) of graph b into
// pmax/psum[(b*PCHUNKS + c)*128 + f].
__global__ void k_pool_partial(const float* __restrict__ x, float* __restrict__ pmax,
                               float* __restrict__ psum, int K3, int chunk) {
    int b = blockIdx.y, c = blockIdx.x, f = threadIdx.x;
    int i0 = c * chunk;
    int i1 = min(K3, i0 + chunk);
    const float* xb = x + (size_t)b * K3 * 128;
    float mx = -FLT_MAX, sm = 0.f;
    for (int i = i0; i < i1; ++i) {
        float v = xb[(size_t)i * 128 + f];
        mx = fmaxf(mx, v);
        sm += v;
    }
    int o = (b * PCHUNKS + c) * 128 + f;
    pmax[o] = mx;
    psum[o] = sm;
}

// stage 2: one block (128 threads) per graph: combine partials + metadata conv + fc + fc2
__global__ void k_final2(const float* __restrict__ pmax, const float* __restrict__ psum,
                         const float* __restrict__ metadata,
                         const float* __restrict__ convm_w, const float* __restrict__ convm_b,
                         const float* __restrict__ fc_w, const float* __restrict__ fc_b,
                         const float* __restrict__ fc2_w, const float* __restrict__ fc2_b,
                         float* __restrict__ out, int K3) {
    int b = blockIdx.x;
    int f = threadIdx.x;   // 0..127
    __shared__ float xc[260];
    __shared__ float red[128];
    float mx = -FLT_MAX, sm = 0.f;
    for (int c = 0; c < PCHUNKS; ++c) {
        int o = (b * PCHUNKS + c) * 128 + f;
        mx = fmaxf(mx, pmax[o]);
        sm += psum[o];
    }
    xc[f] = mx;
    xc[128 + f] = sm / (float)K3;
    if (f < 4) {
        float mv = metadata[b] * convm_w[f] + convm_b[f];
        xc[256 + f] = mv > 0.f ? mv : 0.f;
    }
    __syncthreads();
    float acc = fc_b[f];
    for (int i = 0; i < 260; ++i) acc = fmaf(xc[i], fc_w[i * 128 + f], acc);
    acc = acc > 0.f ? acc : 0.f;
    red[f] = acc * fc2_w[f];
    __syncthreads();
    for (int s2 = 64; s2 > 0; s2 >>= 1) {
        if (f < s2) red[f] += red[f + s2];
        __syncthreads();
    }
    if (f == 0) out[b] = red[0] + fc2_b[0];
}

// ---------------- launch ----------------

extern "C" void kernel_launch(void* const* d_in, const int* in_sizes, int n_in,
                              void* d_out, int out_size, void* d_ws, size_t ws_size,
                              hipStream_t stream) {
    const float* x0       = (const float*)d_in[0];
    const int*   ei       = (const int*)d_in[1];
    const float* metadata = (const float*)d_in[2];
    const float* W[4]  = {(const float*)d_in[3], (const float*)d_in[6],
                          (const float*)d_in[9], (const float*)d_in[12]};
    const float* bs[4] = {(const float*)d_in[4], (const float*)d_in[7],
                          (const float*)d_in[10], (const float*)d_in[13]};
    const float* pv[4] = {(const float*)d_in[5], (const float*)d_in[8],
                          (const float*)d_in[11], (const float*)d_in[14]};
    const float* convm_w = (const float*)d_in[15];
    const float* convm_b = (const float*)d_in[16];
    const float* fc_w    = (const float*)d_in[17];
    const float* fc_b    = (const float*)d_in[18];
    const float* fc2_w   = (const float*)d_in[19];
    const float* fc2_b   = (const float*)d_in[20];

    // workspace bump allocation (all sizes in elements)
    const size_t HMAX = 5243392;   // max M*Fo over layers (layer 3: 40964*128)
    const size_t XMAX = 2621952;   // max pooled-x size (layer 3 out: 20484*128)
    const size_t MMAX = NB * (size_t)N0;   // 163848

    char* p = (char*)d_ws;
    size_t off = 0;
    auto alloc = [&](size_t bytes) -> char* {
        char* r = p + off;
        off = (off + bytes + 255) & ~(size_t)255;
        return r;
    };
    float* h     = (float*)alloc(HMAX * 4);
    float* y     = (float*)alloc(HMAX * 4);
    float* xb0   = (float*)alloc(XMAX * 4);
    float* xb1   = (float*)alloc(XMAX * 4);
    float* deg   = (float*)alloc(MMAX * 4);
    float* score = (float*)alloc(MMAX * 4);
    int*   remap = (int*)alloc(MMAX * 4);
    int*   esrc  = (int*)alloc(E0 * 4);
    int*   edst  = (int*)alloc(E0 * 4);
    float* ew    = (float*)alloc(E0 * 4);
    float* pmax  = (float*)alloc(NB * PCHUNKS * 128 * 4);
    float* psum  = (float*)alloc(NB * PCHUNKS * 128 * 4);
    unsigned long long* T64 = (unsigned long long*)alloc(NB * 8);
    int*   cnt   = (int*)alloc(NB * 4);
    (void)ws_size; (void)n_in; (void)in_sizes; (void)out_size;

    const int Fi[4] = {4, 32, 64, 128};
    const int Fo[4] = {32, 64, 128, 128};
    const int Kk[4] = {20481, 10241, 5121, 2561};

    const int TB = 256;
    k_edges_init<<<(E0 + TB - 1) / TB, TB, 0, stream>>>(ei, esrc, edst, ew);

    int M = NB * N0;
    const float* xin = x0;
    float* xbufs[2] = {xb0, xb1};

    for (int L = 0; L < 4; ++L) {
        int fi = Fi[L], fo = Fo[L];
        int MF = M * fo;
        k_matmul<<<(MF + TB - 1) / TB, TB, 0, stream>>>(xin, W[L], h, M, fi, fo);
        k_deg_init<<<(M + TB - 1) / TB, TB, 0, stream>>>(deg, M);
        k_deg_scatter<<<(E0 + TB - 1) / TB, TB, 0, stream>>>(edst, ew, deg);
        k_y_init<<<(MF + TB - 1) / TB, TB, 0, stream>>>(h, deg, bs[L], y, M, fo);
        int tot = E0 * (fo / 4);
        k_scatter<<<(tot + TB - 1) / TB, TB, 0, stream>>>(esrc, edst, ew, deg, h, y, fo / 4);
        k_relu_score<<<(M + TB - 1) / TB, TB, 0, stream>>>(y, pv[L], score, M, fo);

        int n = M / NB, kk = Kk[L];
        k_topk_thresh<<<NB, 1024, 0, stream>>>(score, T64, cnt, n, kk);
        dim3 gsel((n + 255) / 256, NB);
        k_select_idx<<<gsel, 256, 0, stream>>>(score, T64, cnt, remap, n, kk);
        float* xout = xbufs[L & 1];
        int ctot = M * (fo / 4);
        k_select_copy<<<(ctot + TB - 1) / TB, TB, 0, stream>>>(y, score, remap, xout,
                                                               M, fo / 4);
        if (L < 3)
            k_edge_remap<<<(E0 + TB - 1) / TB, TB, 0, stream>>>(esrc, edst, ew, remap);

        M = NB * kk;
        xin = xout;
    }

    int K3 = Kk[3];
    int chunk = (K3 + PCHUNKS - 1) / PCHUNKS;
    dim3 gpool(PCHUNKS, NB);
    k_pool_partial<<<gpool, 128, 0, stream>>>(xin, pmax, psum, K3, chunk);
    k_final2<<<NB, 128, 0, stream>>>(pmax, psum, metadata, convm_w, convm_b,
                                     fc_w, fc_b, fc2_w, fc2_b, (float*)d_out, K3);
}

// Round 4
// 1035.239 us; speedup vs baseline: 4.4509x; 1.8116x over previous
//
#include <hip/hip_runtime.h>
#include <float.h>
#include <math.h>

#define NB 4            // graphs per batch
#define N0 40962        // nodes per graph at input
#define E0 983088       // total directed edges (fixed across layers; dead edges have w=0)
#define PCHUNKS 40      // stage-1 pooling blocks per graph

// ---------------- helpers ----------------

static __device__ __forceinline__ unsigned long long key64_of(float s, int li) {
    // monotone float->uint mapping (larger float => larger uint)
    unsigned u = __float_as_uint(s);
    u = (u & 0x80000000u) ? ~u : (u | 0x80000000u);
    // tie-break: smaller local index => larger key (ties at score==0.0 are real: all-zero relu rows)
    unsigned low = ~(unsigned)li;
    return ((unsigned long long)u << 32) | (unsigned long long)low;
}

// ---------------- kernels ----------------

__global__ void k_edges_init(const int* __restrict__ ei, int* __restrict__ esrc,
                             int* __restrict__ edst, float* __restrict__ ew) {
    int e = blockIdx.x * blockDim.x + threadIdx.x;
    if (e >= E0) return;
    esrc[e] = ei[e];
    edst[e] = ei[E0 + e];
    ew[e] = 1.0f;
}

// h[m, fo] = sum_fi x[m, fi] * W[fi, fo]
__global__ void k_matmul(const float* __restrict__ x, const float* __restrict__ W,
                         float* __restrict__ h, int M, int Fi, int Fo) {
    int t = blockIdx.x * blockDim.x + threadIdx.x;
    if (t >= M * Fo) return;
    int m = t / Fo, fo = t - m * Fo;
    const float* xr = x + (size_t)m * Fi;
    float acc = 0.f;
    for (int fi = 0; fi < Fi; ++fi) acc = fmaf(xr[fi], W[fi * Fo + fo], acc);
    h[t] = acc;
}

__global__ void k_zero_int(int* __restrict__ a, int n) {
    int i = blockIdx.x * blockDim.x + threadIdx.x;
    if (i < n) a[i] = 0;
}

// count live in-edges per dst node
__global__ void k_deg_count(const int* __restrict__ edst, const float* __restrict__ ew,
                            int* __restrict__ degi) {
    int e = blockIdx.x * blockDim.x + threadIdx.x;
    if (e >= E0) return;
    if (ew[e] != 0.f) atomicAdd(&degi[edst[e]], 1);
}

// exclusive scan, stage 1: 1024 elements per block (256 threads x 4)
__global__ void k_scan1(const int* __restrict__ in, int* __restrict__ out,
                        int* __restrict__ bsum, int M) {
    __shared__ int s[256];
    int t = threadIdx.x;
    int base = blockIdx.x * 1024 + t * 4;
    int d0 = (base + 0 < M) ? in[base + 0] : 0;
    int d1 = (base + 1 < M) ? in[base + 1] : 0;
    int d2 = (base + 2 < M) ? in[base + 2] : 0;
    int d3 = (base + 3 < M) ? in[base + 3] : 0;
    int tsum = d0 + d1 + d2 + d3;
    s[t] = tsum;
    __syncthreads();
    for (int off = 1; off < 256; off <<= 1) {
        int v = (t >= off) ? s[t - off] : 0;
        __syncthreads();
        s[t] += v;
        __syncthreads();
    }
    int texcl = s[t] - tsum;
    if (base + 0 < M) out[base + 0] = texcl;
    if (base + 1 < M) out[base + 1] = texcl + d0;
    if (base + 2 < M) out[base + 2] = texcl + d0 + d1;
    if (base + 3 < M) out[base + 3] = texcl + d0 + d1 + d2;
    if (t == 255) bsum[blockIdx.x] = s[255];
}

// stage 2: single block exclusive scan of block sums (nb <= 256); bsum[nb] = total
__global__ void k_scan2(int* __restrict__ bsum, int nb) {
    __shared__ int s[256];
    int t = threadIdx.x;
    int v = (t < nb) ? bsum[t] : 0;
    s[t] = v;
    __syncthreads();
    for (int off = 1; off < 256; off <<= 1) {
        int u = (t >= off) ? s[t - off] : 0;
        __syncthreads();
        s[t] += u;
        __syncthreads();
    }
    if (t < nb) bsum[t] = s[t] - v;
    if (t == 255) bsum[nb] = s[255];
}

// stage 3: add block offsets; init cursor; write rowptr[M]
__global__ void k_scan3(int* __restrict__ rowptr, const int* __restrict__ bsum,
                        int* __restrict__ cursor, int M, int nb) {
    int i = blockIdx.x * 256 + threadIdx.x;
    if (i < M) {
        int v = rowptr[i] + bsum[i >> 10];
        rowptr[i] = v;
        cursor[i] = v;
    }
    if (i == 0) rowptr[M] = bsum[nb];
}

// dinv[m] = rsqrt(in_deg + 1)
__global__ void k_dinv(const int* __restrict__ rowptr, float* __restrict__ dinv, int M) {
    int m = blockIdx.x * blockDim.x + threadIdx.x;
    if (m >= M) return;
    dinv[m] = rsqrtf((float)(rowptr[m + 1] - rowptr[m]) + 1.0f);
}

// place live edges into CSR buckets (arbitrary order within bucket)
__global__ void k_csr_fill(const int* __restrict__ esrc, const int* __restrict__ edst,
                           const float* __restrict__ ew, int* __restrict__ cursor,
                           int* __restrict__ col) {
    int e = blockIdx.x * blockDim.x + threadIdx.x;
    if (e >= E0) return;
    if (ew[e] != 0.f) {
        int d = edst[e];
        int pos = atomicAdd(&cursor[d], 1);
        col[pos] = esrc[e];
    }
}

// fused GCN aggregate + bias + relu + topk score.
// one row per (wave / sub-wave): y[d] = relu( sum_in h[s]*dinv_s*dinv_d + h[d]/deg_d + bias )
// score[d] = dot(y[d], p) / |p|
template <int FO>
__global__ void k_gather(const float* __restrict__ h, const int* __restrict__ rowptr,
                         const int* __restrict__ col, const float* __restrict__ dinv,
                         const float* __restrict__ p, const float* __restrict__ bias,
                         float* __restrict__ y, float* __restrict__ score, int M) {
    constexpr int LPR = (FO < 64) ? FO : 64;   // lanes per row (32 or 64)
    constexpr int VPL = FO / LPR;              // floats per lane (1 or 2)
    constexpr int RPW = 64 / LPR;              // rows per wave (1 or 2)
    int wave = (blockIdx.x * blockDim.x + threadIdx.x) >> 6;
    int lane = threadIdx.x & 63;
    int sub = lane / LPR;
    int f = lane % LPR;
    int row = wave * RPW + sub;
    if (row >= M) return;
    int rp0 = rowptr[row], rp1 = rowptr[row + 1];
    float dd = dinv[row];
    float invdeg = dd * dd;
    float acc[VPL];
#pragma unroll
    for (int v = 0; v < VPL; ++v) {
        int ff = f * VPL + v;
        acc[v] = h[(size_t)row * FO + ff] * invdeg + bias[ff];
    }
    for (int j = rp0; j < rp1; ++j) {
        int s = col[j];
        float nrm = dd * dinv[s];
#pragma unroll
        for (int v = 0; v < VPL; ++v)
            acc[v] = fmaf(h[(size_t)s * FO + f * VPL + v], nrm, acc[v]);
    }
    float dot = 0.f, pn = 0.f;
#pragma unroll
    for (int v = 0; v < VPL; ++v) {
        float val = acc[v] > 0.f ? acc[v] : 0.f;
        int ff = f * VPL + v;
        y[(size_t)row * FO + ff] = val;
        float pf = p[ff];
        dot = fmaf(val, pf, dot);
        pn = fmaf(pf, pf, pn);
    }
#pragma unroll
    for (int off = LPR / 2; off > 0; off >>= 1) {
        dot += __shfl_xor(dot, off, 64);
        pn += __shfl_xor(pn, off, 64);
    }
    if (f == 0) score[row] = dot * rsqrtf(pn);
}

// one block (1024 threads) per graph: radix-select the k-th largest composite key -> T64[b];
// zero cnt[b]. Early-exits when the k-th key's prefix is unique at some level.
__global__ void k_topk_thresh(const float* __restrict__ score, unsigned long long* __restrict__ T64,
                              int* __restrict__ cnt, int n, int k) {
    int b = blockIdx.x;
    const float* sc = score + (size_t)b * n;
    __shared__ unsigned int hist[256];
    __shared__ unsigned long long s_prefix;
    __shared__ int s_r;
    __shared__ int s_done;
    if (threadIdx.x == 0) { s_prefix = 0ULL; s_r = k; s_done = 0; }
    __syncthreads();
    for (int shift = 56; shift >= 0; shift -= 8) {
        if (s_done) break;
        for (int i = threadIdx.x; i < 256; i += blockDim.x) hist[i] = 0u;
        __syncthreads();
        unsigned long long prefix = s_prefix;
        int hs = shift + 8;
        for (int i = threadIdx.x; i < n; i += blockDim.x) {
            unsigned long long key = key64_of(sc[i], i);
            bool match = (hs >= 64) || ((key >> hs) == (prefix >> hs));
            if (match) {
                unsigned d = (unsigned)((key >> shift) & 255ULL);
                atomicAdd(&hist[d], 1u);
            }
        }
        __syncthreads();
        if (threadIdx.x == 0) {
            int r = s_r;
            unsigned long long pfx = s_prefix;
            for (int d = 255; d >= 0; --d) {
                int c = (int)hist[d];
                if (r <= c) {
                    pfx |= ((unsigned long long)d) << shift;
                    if (r == c) s_done = 1;   // all prefix-matching keys kept; low bits stay 0
                    break;
                }
                r -= c;
            }
            s_prefix = pfx;
            s_r = r;
        }
        __syncthreads();
    }
    if (threadIdx.x == 0) { T64[b] = s_prefix; cnt[b] = 0; }
}

// phase A: keep flag -> new index via wave-aggregated block atomic; score := tanh(score) for kept
// grid: (ceil(n/256), NB), block 256 (4 waves)
__global__ void k_select_idx(float* __restrict__ score,
                             const unsigned long long* __restrict__ T64, int* __restrict__ cnt,
                             int* __restrict__ remap, int n, int k) {
    int b = blockIdx.y;
    int i = blockIdx.x * 256 + threadIdx.x;
    int m = b * n + i;
    bool keep = false;
    float s = 0.f;
    if (i < n) {
        s = score[m];
        keep = key64_of(s, i) >= T64[b];
    }
    unsigned long long mask = __ballot(keep);
    int lane = threadIdx.x & 63;
    int wv = threadIdx.x >> 6;
    int lp = __popcll(mask & ((1ULL << lane) - 1ULL));
    __shared__ int woff[4];
    __shared__ int blockBase;
    if (lane == 0) woff[wv] = __popcll(mask);
    __syncthreads();
    if (threadIdx.x == 0) {
        int t0 = woff[0], t1 = woff[1], t2 = woff[2], t3 = woff[3];
        woff[0] = 0; woff[1] = t0; woff[2] = t0 + t1; woff[3] = t0 + t1 + t2;
        blockBase = atomicAdd(&cnt[b], t0 + t1 + t2 + t3);
    }
    __syncthreads();
    if (i < n) {
        if (keep) {
            remap[m] = b * k + blockBase + woff[wv] + lp;
            score[m] = tanhf(s);
        } else {
            remap[m] = -1;
        }
    }
}

// phase B: coalesced float4 row copy, xout[remap[m]] = y[m] * score[m] (score holds tanh)
__global__ void k_select_copy(const float* __restrict__ y, const float* __restrict__ score,
                              const int* __restrict__ remap, float* __restrict__ xout,
                              int M, int Fo4) {
    int t = blockIdx.x * blockDim.x + threadIdx.x;
    if (t >= M * Fo4) return;
    int m = t / Fo4, c = t - m * Fo4;
    int ni = remap[m];
    if (ni < 0) return;
    float4 v = ((const float4*)y)[(size_t)m * Fo4 + c];
    float s = score[m];
    float4 o; o.x = v.x * s; o.y = v.y * s; o.z = v.z * s; o.w = v.w * s;
    ((float4*)xout)[(size_t)ni * Fo4 + c] = o;
}

__global__ void k_edge_remap(int* __restrict__ esrc, int* __restrict__ edst,
                             float* __restrict__ ew, const int* __restrict__ remap) {
    int e = blockIdx.x * blockDim.x + threadIdx.x;
    if (e >= E0) return;
    float w = ew[e];
    if (w != 0.f) {
        int ns = remap[esrc[e]];
        int nd = remap[edst[e]];
        if (ns >= 0 && nd >= 0) { esrc[e] = ns; edst[e] = nd; return; }
    }
    esrc[e] = 0; edst[e] = 0; ew[e] = 0.f;
}

// stage 1 of final pooling: grid (PCHUNKS, NB), block 128.
__global__ void k_pool_partial(const float* __restrict__ x, float* __restrict__ pmax,
                               float* __restrict__ psum, int K3, int chunk) {
    int b = blockIdx.y, c = blockIdx.x, f = threadIdx.x;
    int i0 = c * chunk;
    int i1 = min(K3, i0 + chunk);
    const float* xb = x + (size_t)b * K3 * 128;
    float mx = -FLT_MAX, sm = 0.f;
    for (int i = i0; i < i1; ++i) {
        float v = xb[(size_t)i * 128 + f];
        mx = fmaxf(mx, v);
        sm += v;
    }
    int o = (b * PCHUNKS + c) * 128 + f;
    pmax[o] = mx;
    psum[o] = sm;
}

// stage 2: one block (128 threads) per graph: combine partials + metadata conv + fc + fc2
__global__ void k_final2(const float* __restrict__ pmax, const float* __restrict__ psum,
                         const float* __restrict__ metadata,
                         const float* __restrict__ convm_w, const float* __restrict__ convm_b,
                         const float* __restrict__ fc_w, const float* __restrict__ fc_b,
                         const float* __restrict__ fc2_w, const float* __restrict__ fc2_b,
                         float* __restrict__ out, int K3) {
    int b = blockIdx.x;
    int f = threadIdx.x;   // 0..127
    __shared__ float xc[260];
    __shared__ float red[128];
    float mx = -FLT_MAX, sm = 0.f;
    for (int c = 0; c < PCHUNKS; ++c) {
        int o = (b * PCHUNKS + c) * 128 + f;
        mx = fmaxf(mx, pmax[o]);
        sm += psum[o];
    }
    xc[f] = mx;
    xc[128 + f] = sm / (float)K3;
    if (f < 4) {
        float mv = metadata[b] * convm_w[f] + convm_b[f];
        xc[256 + f] = mv > 0.f ? mv : 0.f;
    }
    __syncthreads();
    float acc = fc_b[f];
    for (int i = 0; i < 260; ++i) acc = fmaf(xc[i], fc_w[i * 128 + f], acc);
    acc = acc > 0.f ? acc : 0.f;
    red[f] = acc * fc2_w[f];
    __syncthreads();
    for (int s2 = 64; s2 > 0; s2 >>= 1) {
        if (f < s2) red[f] += red[f + s2];
        __syncthreads();
    }
    if (f == 0) out[b] = red[0] + fc2_b[0];
}

// ---------------- launch ----------------

extern "C" void kernel_launch(void* const* d_in, const int* in_sizes, int n_in,
                              void* d_out, int out_size, void* d_ws, size_t ws_size,
                              hipStream_t stream) {
    const float* x0       = (const float*)d_in[0];
    const int*   ei       = (const int*)d_in[1];
    const float* metadata = (const float*)d_in[2];
    const float* W[4]  = {(const float*)d_in[3], (const float*)d_in[6],
                          (const float*)d_in[9], (const float*)d_in[12]};
    const float* bs[4] = {(const float*)d_in[4], (const float*)d_in[7],
                          (const float*)d_in[10], (const float*)d_in[13]};
    const float* pv[4] = {(const float*)d_in[5], (const float*)d_in[8],
                          (const float*)d_in[11], (const float*)d_in[14]};
    const float* convm_w = (const float*)d_in[15];
    const float* convm_b = (const float*)d_in[16];
    const float* fc_w    = (const float*)d_in[17];
    const float* fc_b    = (const float*)d_in[18];
    const float* fc2_w   = (const float*)d_in[19];
    const float* fc2_b   = (const float*)d_in[20];

    // workspace bump allocation
    const size_t HMAX = 5243392;   // max M*Fo over layers (layer 3: 40964*128)
    const size_t XMAX = 2621952;   // max pooled-x size (layer 3 out: 20484*128)
    const size_t MMAX = NB * (size_t)N0;   // 163848

    char* p = (char*)d_ws;
    size_t off = 0;
    auto alloc = [&](size_t bytes) -> char* {
        char* r = p + off;
        off = (off + bytes + 255) & ~(size_t)255;
        return r;
    };
    float* h     = (float*)alloc(HMAX * 4);
    float* y     = (float*)alloc(HMAX * 4);
    float* xb0   = (float*)alloc(XMAX * 4);
    float* xb1   = (float*)alloc(XMAX * 4);
    float* dinv  = (float*)alloc(MMAX * 4);
    float* score = (float*)alloc(MMAX * 4);
    int*   remap = (int*)alloc(MMAX * 4);
    int*   degi  = (int*)alloc(MMAX * 4);
    int*   rowptr= (int*)alloc((MMAX + 1) * 4);
    int*   cursor= (int*)alloc(MMAX * 4);
    int*   col   = (int*)alloc(E0 * 4);
    int*   bsum  = (int*)alloc(260 * 4);
    int*   esrc  = (int*)alloc(E0 * 4);
    int*   edst  = (int*)alloc(E0 * 4);
    float* ew    = (float*)alloc(E0 * 4);
    float* pmax  = (float*)alloc(NB * PCHUNKS * 128 * 4);
    float* psum  = (float*)alloc(NB * PCHUNKS * 128 * 4);
    unsigned long long* T64 = (unsigned long long*)alloc(NB * 8);
    int*   cnt   = (int*)alloc(NB * 4);
    (void)ws_size; (void)n_in; (void)in_sizes; (void)out_size;

    const int Fi[4] = {4, 32, 64, 128};
    const int Fo[4] = {32, 64, 128, 128};
    const int Kk[4] = {20481, 10241, 5121, 2561};

    const int TB = 256;
    const int EG = (E0 + TB - 1) / TB;
    k_edges_init<<<EG, TB, 0, stream>>>(ei, esrc, edst, ew);

    int M = NB * N0;
    const float* xin = x0;
    float* xbufs[2] = {xb0, xb1};

    for (int L = 0; L < 4; ++L) {
        int fi = Fi[L], fo = Fo[L];
        int MF = M * fo;
        k_matmul<<<(MF + TB - 1) / TB, TB, 0, stream>>>(xin, W[L], h, M, fi, fo);

        // ---- CSR build ----
        k_zero_int<<<(M + TB - 1) / TB, TB, 0, stream>>>(degi, M);
        k_deg_count<<<EG, TB, 0, stream>>>(edst, ew, degi);
        int nb = (M + 1023) / 1024;
        k_scan1<<<nb, 256, 0, stream>>>(degi, rowptr, bsum, M);
        k_scan2<<<1, 256, 0, stream>>>(bsum, nb);
        k_scan3<<<(M + 255) / 256, 256, 0, stream>>>(rowptr, bsum, cursor, M, nb);
        k_dinv<<<(M + TB - 1) / TB, TB, 0, stream>>>(rowptr, dinv, M);
        k_csr_fill<<<EG, TB, 0, stream>>>(esrc, edst, ew, cursor, col);

        // ---- fused gather (aggregate + bias + relu + score) ----
        int rowsPerBlock = (fo == 32) ? 8 : 4;
        int gblocks = (M + rowsPerBlock - 1) / rowsPerBlock;
        if (fo == 32)
            k_gather<32><<<gblocks, 256, 0, stream>>>(h, rowptr, col, dinv, pv[L], bs[L], y, score, M);
        else if (fo == 64)
            k_gather<64><<<gblocks, 256, 0, stream>>>(h, rowptr, col, dinv, pv[L], bs[L], y, score, M);
        else
            k_gather<128><<<gblocks, 256, 0, stream>>>(h, rowptr, col, dinv, pv[L], bs[L], y, score, M);

        // ---- top-k pooling ----
        int n = M / NB, kk = Kk[L];
        k_topk_thresh<<<NB, 1024, 0, stream>>>(score, T64, cnt, n, kk);
        dim3 gsel((n + 255) / 256, NB);
        k_select_idx<<<gsel, 256, 0, stream>>>(score, T64, cnt, remap, n, kk);
        float* xout = xbufs[L & 1];
        int ctot = M * (fo / 4);
        k_select_copy<<<(ctot + TB - 1) / TB, TB, 0, stream>>>(y, score, remap, xout,
                                                               M, fo / 4);
        if (L < 3)
            k_edge_remap<<<EG, TB, 0, stream>>>(esrc, edst, ew, remap);

        M = NB * kk;
        xin = xout;
    }

    int K3 = Kk[3];
    int chunk = (K3 + PCHUNKS - 1) / PCHUNKS;
    dim3 gpool(PCHUNKS, NB);
    k_pool_partial<<<gpool, 128, 0, stream>>>(xin, pmax, psum, K3, chunk);
    k_final2<<<NB, 128, 0, stream>>>(pmax, psum, metadata, convm_w, convm_b,
                                     fc_w, fc_b, fc2_w, fc2_b, (float*)d_out, K3);
}